// Round 4
// baseline (582.144 us; speedup 1.0000x reference)
//
#include <hip/hip_runtime.h>
#include <hip/hip_bf16.h>

typedef __attribute__((ext_vector_type(8))) __bf16 bf16x8;
typedef __attribute__((ext_vector_type(4))) float f32x4;
typedef __attribute__((ext_vector_type(4))) unsigned short u16x4;
typedef unsigned short u16;

#define MFMA16 __builtin_amdgcn_mfma_f32_16x16x32_bf16

#if __has_builtin(__builtin_amdgcn_exp2f)
#define EXP2F __builtin_amdgcn_exp2f
#else
#define EXP2F(x) __expf((x) * 0.69314718056f)
#endif

__device__ inline u16 f32_to_bf16_bits(float f) {
    unsigned u = __builtin_bit_cast(unsigned, f);
    unsigned r = u + 0x7FFFu + ((u >> 16) & 1u);
    return (u16)(r >> 16);
}

__device__ inline void g2l16(const void* g, void* l) {
    __builtin_amdgcn_global_load_lds(
        (const __attribute__((address_space(1))) unsigned int*)g,
        (__attribute__((address_space(3))) unsigned int*)l,
        16, 0, 0);
}

// ---------------- convert: f32 -> bf16 (vectorized) ----------------
__global__ void cvt_bf16_kernel(const float* __restrict__ in, u16* __restrict__ out, int n) {
    int i = (blockIdx.x * 256 + threadIdx.x) * 4;
    if (i >= n) return;
    f32x4 v = *(const f32x4*)&in[i];
    u16x4 r;
#pragma unroll
    for (int j = 0; j < 4; ++j) r[j] = f32_to_bf16_bits(v[j]);
    *(u16x4*)&out[i] = r;
}

// ---------------- convert + transpose: W[K][N] f32 -> WT[N][K] bf16 ----------------
__global__ void cvt_t_kernel(const float* __restrict__ W, u16* __restrict__ WT, int K, int N) {
    int idx = blockIdx.x * 256 + threadIdx.x;
    int k = idx / N;
    int n = idx - k * N;
    WT[(size_t)n * K + k] = f32_to_bf16_bits(W[idx]);
}

// ---------------- GEMM: C[M][N] = A[M][K] * BT[N][K]^T + bias ----------------
template <int STORE_BF16>
__global__ __launch_bounds__(256) void gemm_nt(
    const u16* __restrict__ A, const u16* __restrict__ BT,
    const float* __restrict__ bias, void* __restrict__ Cv,
    int M, int N, int K)
{
    __shared__ __align__(16) u16 As[128 * 64];
    __shared__ __align__(16) u16 Bs[128 * 64];
    const int tid = threadIdx.x;
    const int w = tid >> 6, l = tid & 63;
    const int lr = l & 15, lh = l >> 4;
    const int wr = (w >> 1) * 64, wc = (w & 1) * 64;
    const int m0 = blockIdx.y * 128, n0 = blockIdx.x * 128;

    f32x4 acc[4][4];
#pragma unroll
    for (int m = 0; m < 4; ++m)
#pragma unroll
        for (int n = 0; n < 4; ++n) acc[m][n] = (f32x4)(0.0f);

    for (int k0 = 0; k0 < K; k0 += 64) {
        __syncthreads();
#pragma unroll
        for (int p = 0; p < 4; ++p) {
            int f = p * 256 + tid;
            int r = f >> 3, kk = (f & 7) << 3;
            g2l16(A + (size_t)(m0 + r) * K + (k0 + kk), &As[(p * 4 + w) * 512]);
            g2l16(BT + (size_t)(n0 + r) * K + (k0 + kk), &Bs[(p * 4 + w) * 512]);
        }
        __syncthreads();
#pragma unroll
        for (int ks = 0; ks < 2; ++ks) {
            bf16x8 af[4], bfr[4];
#pragma unroll
            for (int m = 0; m < 4; ++m)
                af[m] = *(const bf16x8*)&As[(wr + m * 16 + lr) * 64 + ks * 32 + lh * 8];
#pragma unroll
            for (int n = 0; n < 4; ++n)
                bfr[n] = *(const bf16x8*)&Bs[(wc + n * 16 + lr) * 64 + ks * 32 + lh * 8];
#pragma unroll
            for (int m = 0; m < 4; ++m)
#pragma unroll
                for (int n = 0; n < 4; ++n)
                    acc[m][n] = MFMA16(af[m], bfr[n], acc[m][n], 0, 0, 0);
        }
    }

#pragma unroll
    for (int m = 0; m < 4; ++m) {
        int row = m0 + wr + m * 16 + lh * 4;
#pragma unroll
        for (int n = 0; n < 4; ++n) {
            int col = n0 + wc + n * 16 + lr;
            float bs = bias[col];
#pragma unroll
            for (int j = 0; j < 4; ++j) {
                float v = acc[m][n][j] + bs;
                if (STORE_BF16)
                    ((u16*)Cv)[(size_t)(row + j) * N + col] = f32_to_bf16_bits(v);
                else
                    ((float*)Cv)[(size_t)(row + j) * N + col] = v;
            }
        }
    }
}

// ---------------- causal flash attention v3 ----------------
// QBLK=256 (8 waves x 32 rows), KVBLK=64. Swapped QK^T (S^T = K*Q^T).
// K double-buffered in LDS via global_load_lds, per-row XOR swizzle (key=row&7).
// V reg-staged, transposed into VT with double-key swizzle ((d&7)^(d>>3)).
// P per-wave [16][64] with (q&7) XOR key. exp2-domain online softmax.
__global__ __launch_bounds__(512, 4) void attn_kernel(
    const u16* __restrict__ qkv, u16* __restrict__ ctx)
{
    __shared__ __align__(16) u16 SM[24576];   // K dbuf 8K | V dbuf 8K | P 8x1K (u16)

    const int bid = blockIdx.x;
    const int swz = (bid & 7) * 64 + (bid >> 3);   // 8 heads per XCD
    const int bh = swz >> 3;
    const int qt = 7 - (swz & 7);                  // big q-tiles dispatched first
    const int b = bh >> 4, h = bh & 15;
    const size_t rowbase = (size_t)b * 2048;
    const int q0 = qt * 256;
    const int nt = 4 * qt + 4;
    const int tid = threadIdx.x, w = tid >> 6, l = tid & 63;
    const int lr = l & 15, lh = l >> 4;
    u16* const PL = SM + 16384 + w * 1024;         // [16][64] per wave, (q&7) key

    // staging geometry: wave w stages rows w*8..w*8+7 of the 64-row K/V tile
    const int rstage = w * 8 + (l >> 3);
    const int cstage = l & 7;                       // dest col-chunk
    const int kchunk = cstage ^ (l >> 3);           // inverse-swizzle src chunk (key=row&7)

    // Q fragments (MFMA B-operand): lane holds Q[q=base+lr][k=lh*8..+7 (+ks*32)]
    bf16x8 qf[2][2];
#pragma unroll
    for (int s = 0; s < 2; ++s) {
        const u16* qp = qkv + (rowbase + q0 + w * 32 + s * 16 + lr) * 3072 + h * 64 + lh * 8;
        qf[s][0] = *(const bf16x8*)qp;
        qf[s][1] = *(const bf16x8*)(qp + 32);
    }

    f32x4 ot[2][4];
#pragma unroll
    for (int s = 0; s < 2; ++s)
#pragma unroll
        for (int dt = 0; dt < 4; ++dt) ot[s][dt] = (f32x4)(0.0f);
    float m_run[2] = {-3e38f, -3e38f};
    float l_run[2] = {0.0f, 0.0f};

    const float SC = 0.125f * 1.44269504089f;   // 1/sqrt(d) folded with log2(e)

    bf16x8 vreg;

    // ---- prologue: stage tile 0 ----
    g2l16(qkv + (rowbase + rstage) * 3072 + 1024 + h * 64 + kchunk * 8, SM + w * 512);
    vreg = *(const bf16x8*)(qkv + (rowbase + rstage) * 3072 + 2048 + h * 64 + cstage * 8);
    asm volatile("s_waitcnt vmcnt(0)" ::: "memory");
#pragma unroll
    for (int i = 0; i < 8; ++i) {
        const int d = cstage * 8 + i;
        SM[8192 + (((d * 64 + rstage) ^ (((i ^ cstage) & 7) << 3)))] = ((const u16*)&vreg)[i];
    }
    __syncthreads();

    for (int t = 0; t < nt; ++t) {
        const int c = t & 1;
        const int kb = t * 64;
        u16* const Kb = SM + (c ? 4096 : 0);
        u16* const Vb = SM + 8192 + (c ? 4096 : 0);

        // issue next-tile staging (K -> LDS direct, V -> regs) before compute
        if (t + 1 < nt) {
            const int kb2 = kb + 64;
            g2l16(qkv + (rowbase + kb2 + rstage) * 3072 + 1024 + h * 64 + kchunk * 8,
                  SM + (c ? 0 : 4096) + w * 512);
            vreg = *(const bf16x8*)(qkv + (rowbase + kb2 + rstage) * 3072 + 2048 + h * 64 + cstage * 8);
        }

        if (kb <= q0 + w * 32 + 31) {   // wave has at least one visible strip
            // K A-fragments, shared by both strips (swizzled ds_read_b128, key=lr&7)
            bf16x8 kf[4][2];
#pragma unroll
            for (int kt = 0; kt < 4; ++kt)
#pragma unroll
                for (int ks = 0; ks < 2; ++ks)
                    kf[kt][ks] = *(const bf16x8*)&Kb[((kt * 16 + lr) * 64 + ks * 32 + lh * 8) ^ ((lr & 7) << 3)];
#pragma unroll
            for (int s = 0; s < 2; ++s) {
                const int qbase = q0 + w * 32 + s * 16;
                if (kb > qbase + 15) continue;
                // S^T[key][q] = K * Q^T : lane owns q = lr
                f32x4 sf[4];
                __builtin_amdgcn_s_setprio(1);
#pragma unroll
                for (int kt = 0; kt < 4; ++kt) {
                    f32x4 z = (f32x4)(0.0f);
                    z = MFMA16(kf[kt][0], qf[s][0], z, 0, 0, 0);
                    z = MFMA16(kf[kt][1], qf[s][1], z, 0, 0, 0);
                    sf[kt] = z;
                }
                __builtin_amdgcn_s_setprio(0);
                const int qrow = qbase + lr;
                const bool notfull = (kb + 63 > qbase);
                float mt = -3e38f;
#pragma unroll
                for (int kt = 0; kt < 4; ++kt)
#pragma unroll
                    for (int j = 0; j < 4; ++j) {
                        float v = sf[kt][j] * SC;   // exp2 domain
                        if (notfull && (kb + kt * 16 + lh * 4 + j > qrow)) v = -3e38f;
                        sf[kt][j] = v;
                        mt = fmaxf(mt, v);
                    }
                mt = fmaxf(mt, __shfl_xor(mt, 16));
                mt = fmaxf(mt, __shfl_xor(mt, 32));
                const float mn = fmaxf(m_run[s], mt);
                const float alpha = EXP2F(m_run[s] - mn);
                m_run[s] = mn;
                float rs = 0.0f;
#pragma unroll
                for (int kt = 0; kt < 4; ++kt)
#pragma unroll
                    for (int j = 0; j < 4; ++j) {
                        const float pp = EXP2F(sf[kt][j] - mn);
                        sf[kt][j] = pp;
                        rs += pp;
                    }
                rs += __shfl_xor(rs, 16);
                rs += __shfl_xor(rs, 32);
                l_run[s] = l_run[s] * alpha + rs;
#pragma unroll
                for (int dt = 0; dt < 4; ++dt)
#pragma unroll
                    for (int j = 0; j < 4; ++j) ot[s][dt][j] *= alpha;
                // P^T lane-local -> per-wave P_lds [q][key], (q&7) XOR key
#pragma unroll
                for (int kt = 0; kt < 4; ++kt) {
                    u16x4 pk;
#pragma unroll
                    for (int j = 0; j < 4; ++j) pk[j] = f32_to_bf16_bits(sf[kt][j]);
                    *(u16x4*)&PL[(lr * 64 + kt * 16 + lh * 4) ^ ((lr & 7) << 3)] = pk;
                }
                // PV: O^T[d][q] += V^T * P^T
                __builtin_amdgcn_s_setprio(1);
#pragma unroll
                for (int ks = 0; ks < 2; ++ks) {
                    const bf16x8 pb = *(const bf16x8*)&PL[(lr * 64 + ks * 32 + lh * 8) ^ ((lr & 7) << 3)];
#pragma unroll
                    for (int dt = 0; dt < 4; ++dt) {
                        const int vkey = ((lr & 7) ^ (dt * 2 + (lr >> 3))) & 7;
                        const bf16x8 vf = *(const bf16x8*)&Vb[((dt * 16 + lr) * 64 + ks * 32 + lh * 8) ^ (vkey << 3)];
                        ot[s][dt] = MFMA16(vf, pb, ot[s][dt], 0, 0, 0);
                    }
                }
                __builtin_amdgcn_s_setprio(0);
            }
        }

        asm volatile("s_waitcnt vmcnt(0)" ::: "memory");
        __syncthreads();
        if (t + 1 < nt) {
            u16* const Vn = SM + 8192 + (c ? 0 : 4096);
#pragma unroll
            for (int i = 0; i < 8; ++i) {
                const int d = cstage * 8 + i;
                Vn[((d * 64 + rstage) ^ (((i ^ cstage) & 7) << 3))] = ((const u16*)&vreg)[i];
            }
        }
        __syncthreads();
    }

    // ---- epilogue: O^T -> LDS transpose -> coalesced bf16 stores ----
    u16* const out_l = SM + w * 2304;   // [32][72] per wave, reuses K/V/P space
#pragma unroll
    for (int s = 0; s < 2; ++s) {
        const float inv = 1.0f / l_run[s];
#pragma unroll
        for (int dt = 0; dt < 4; ++dt)
#pragma unroll
            for (int j = 0; j < 4; ++j)
                out_l[(s * 16 + lr) * 72 + dt * 16 + lh * 4 + j] =
                    f32_to_bf16_bits(ot[s][dt][j] * inv);
    }
    __syncthreads();
#pragma unroll
    for (int r4 = 0; r4 < 4; ++r4) {
        const int row = r4 * 8 + (l >> 3);
        const bf16x8 v = *(const bf16x8*)&out_l[row * 72 + (l & 7) * 8];
        *(bf16x8*)(ctx + (rowbase + q0 + w * 32 + row) * 1024 + h * 64 + (l & 7) * 8) = v;
    }
}

extern "C" void kernel_launch(void* const* d_in, const int* in_sizes, int n_in,
                              void* d_out, int out_size, void* d_ws, size_t ws_size,
                              hipStream_t stream) {
    const float* x      = (const float*)d_in[0];
    const float* W_qkv  = (const float*)d_in[1];
    const float* b_qkv  = (const float*)d_in[2];
    const float* W_o    = (const float*)d_in[3];
    const float* b_o    = (const float*)d_in[4];
    float* out = (float*)d_out;

    const int M = 4 * 2048;     // 8192 rows
    const int C = 1024;
    u16* qkv   = (u16*)d_ws;                       // [8192][3072]
    u16* xb    = qkv   + (size_t)M * 3 * C;        // [8192][1024]
    u16* wqkvt = xb    + (size_t)M * C;            // [3072][1024]
    u16* ctx   = wqkvt + (size_t)3 * C * C;        // [8192][1024]
    u16* wot   = ctx   + (size_t)M * C;            // [1024][1024]

    cvt_bf16_kernel<<<(M * C) / (256 * 4), 256, 0, stream>>>(x, xb, M * C);
    cvt_t_kernel<<<(3 * C * C) / 256, 256, 0, stream>>>(W_qkv, wqkvt, C, 3 * C);
    cvt_t_kernel<<<(C * C) / 256, 256, 0, stream>>>(W_o, wot, C, C);

    gemm_nt<1><<<dim3(3 * C / 128, M / 128), 256, 0, stream>>>(xb, wqkvt, b_qkv, qkv, M, 3 * C, C);

    attn_kernel<<<512, 512, 0, stream>>>(qkv, ctx);

    gemm_nt<0><<<dim3(C / 128, M / 128), 256, 0, stream>>>(ctx, wot, b_o, out, M, C, C);
}

// Round 5
// 289.837 us; speedup vs baseline: 2.0085x; 2.0085x over previous
//
#include <hip/hip_runtime.h>
#include <hip/hip_bf16.h>

typedef __attribute__((ext_vector_type(8))) __bf16 bf16x8;
typedef __attribute__((ext_vector_type(4))) float f32x4;
typedef __attribute__((ext_vector_type(4))) unsigned short u16x4;
typedef unsigned short u16;

#define MFMA16 __builtin_amdgcn_mfma_f32_16x16x32_bf16

#if __has_builtin(__builtin_amdgcn_exp2f)
#define EXP2F __builtin_amdgcn_exp2f
#else
#define EXP2F(x) __expf((x) * 0.69314718056f)
#endif

__device__ inline u16 f32_to_bf16_bits(float f) {
    unsigned u = __builtin_bit_cast(unsigned, f);
    unsigned r = u + 0x7FFFu + ((u >> 16) & 1u);
    return (u16)(r >> 16);
}

__device__ inline void g2l16(const void* g, void* l) {
    __builtin_amdgcn_global_load_lds(
        (const __attribute__((address_space(1))) unsigned int*)g,
        (__attribute__((address_space(3))) unsigned int*)l,
        16, 0, 0);
}

// ---------------- convert: f32 -> bf16 (vectorized) ----------------
__global__ void cvt_bf16_kernel(const float* __restrict__ in, u16* __restrict__ out, int n) {
    int i = (blockIdx.x * 256 + threadIdx.x) * 4;
    if (i >= n) return;
    f32x4 v = *(const f32x4*)&in[i];
    u16x4 r;
#pragma unroll
    for (int j = 0; j < 4; ++j) r[j] = f32_to_bf16_bits(v[j]);
    *(u16x4*)&out[i] = r;
}

// ---------------- convert + transpose: W[K][N] f32 -> WT[N][K] bf16 ----------------
__global__ void cvt_t_kernel(const float* __restrict__ W, u16* __restrict__ WT, int K, int N) {
    int idx = blockIdx.x * 256 + threadIdx.x;
    int k = idx / N;
    int n = idx - k * N;
    WT[(size_t)n * K + k] = f32_to_bf16_bits(W[idx]);
}

// ---------------- GEMM: C[M][N] = A[M][K] * BT[N][K]^T + bias ----------------
template <int STORE_BF16>
__global__ __launch_bounds__(256) void gemm_nt(
    const u16* __restrict__ A, const u16* __restrict__ BT,
    const float* __restrict__ bias, void* __restrict__ Cv,
    int M, int N, int K)
{
    __shared__ __align__(16) u16 As[128 * 64];
    __shared__ __align__(16) u16 Bs[128 * 64];
    const int tid = threadIdx.x;
    const int w = tid >> 6, l = tid & 63;
    const int lr = l & 15, lh = l >> 4;
    const int wr = (w >> 1) * 64, wc = (w & 1) * 64;
    const int m0 = blockIdx.y * 128, n0 = blockIdx.x * 128;

    f32x4 acc[4][4];
#pragma unroll
    for (int m = 0; m < 4; ++m)
#pragma unroll
        for (int n = 0; n < 4; ++n) acc[m][n] = (f32x4)(0.0f);

    for (int k0 = 0; k0 < K; k0 += 64) {
        __syncthreads();
#pragma unroll
        for (int p = 0; p < 4; ++p) {
            int f = p * 256 + tid;
            int r = f >> 3, kk = (f & 7) << 3;
            g2l16(A + (size_t)(m0 + r) * K + (k0 + kk), &As[(p * 4 + w) * 512]);
            g2l16(BT + (size_t)(n0 + r) * K + (k0 + kk), &Bs[(p * 4 + w) * 512]);
        }
        __syncthreads();
#pragma unroll
        for (int ks = 0; ks < 2; ++ks) {
            bf16x8 af[4], bfr[4];
#pragma unroll
            for (int m = 0; m < 4; ++m)
                af[m] = *(const bf16x8*)&As[(wr + m * 16 + lr) * 64 + ks * 32 + lh * 8];
#pragma unroll
            for (int n = 0; n < 4; ++n)
                bfr[n] = *(const bf16x8*)&Bs[(wc + n * 16 + lr) * 64 + ks * 32 + lh * 8];
#pragma unroll
            for (int m = 0; m < 4; ++m)
#pragma unroll
                for (int n = 0; n < 4; ++n)
                    acc[m][n] = MFMA16(af[m], bfr[n], acc[m][n], 0, 0, 0);
        }
    }

#pragma unroll
    for (int m = 0; m < 4; ++m) {
        int row = m0 + wr + m * 16 + lh * 4;
#pragma unroll
        for (int n = 0; n < 4; ++n) {
            int col = n0 + wc + n * 16 + lr;
            float bs = bias[col];
#pragma unroll
            for (int j = 0; j < 4; ++j) {
                float v = acc[m][n][j] + bs;
                if (STORE_BF16)
                    ((u16*)Cv)[(size_t)(row + j) * N + col] = f32_to_bf16_bits(v);
                else
                    ((float*)Cv)[(size_t)(row + j) * N + col] = v;
            }
        }
    }
}

// ---------------- causal flash attention v3.1 ----------------
// QBLK=256 (8 waves x 32 rows), KVBLK=64. Swapped QK^T (S^T = K*Q^T).
// K double-buffered in LDS via global_load_lds, per-row XOR swizzle (key=row&7).
// V reg-staged, transposed into VT with double-key swizzle ((d&7)^(d>>3)).
// P per-wave [16][64] with (q&7) XOR key. exp2-domain online softmax.
// launch_bounds (512,2): 128-VGPR cap — (512,4) forced 64 VGPR -> scratch spill.
__global__ __launch_bounds__(512, 2) void attn_kernel(
    const u16* __restrict__ qkv, u16* __restrict__ ctx)
{
    __shared__ __align__(16) u16 SM[24576];   // K dbuf 8K | V dbuf 8K | P 8x1K (u16)

    const int bid = blockIdx.x;
    const int swz = (bid & 7) * 64 + (bid >> 3);   // 8 heads per XCD
    const int bh = swz >> 3;
    const int qt = 7 - (swz & 7);                  // big q-tiles dispatched first
    const int b = bh >> 4, h = bh & 15;
    const size_t rowbase = (size_t)b * 2048;
    const int q0 = qt * 256;
    const int nt = 4 * qt + 4;
    const int tid = threadIdx.x, w = tid >> 6, l = tid & 63;
    const int lr = l & 15, lh = l >> 4;
    u16* const PL = SM + 16384 + w * 1024;         // [16][64] per wave, (q&7) key

    // staging geometry: wave w stages rows w*8..w*8+7 of the 64-row K/V tile
    const int rstage = w * 8 + (l >> 3);
    const int cstage = l & 7;                       // dest col-chunk
    const int kchunk = cstage ^ (l >> 3);           // inverse-swizzle src chunk (key=row&7)

    // Q fragments (MFMA B-operand): lane holds Q[q=base+lr][k=lh*8..+7 (+ks*32)]
    bf16x8 qf[2][2];
#pragma unroll
    for (int s = 0; s < 2; ++s) {
        const u16* qp = qkv + (rowbase + q0 + w * 32 + s * 16 + lr) * 3072 + h * 64 + lh * 8;
        qf[s][0] = *(const bf16x8*)qp;
        qf[s][1] = *(const bf16x8*)(qp + 32);
    }

    f32x4 ot[2][4];
#pragma unroll
    for (int s = 0; s < 2; ++s)
#pragma unroll
        for (int dt = 0; dt < 4; ++dt) ot[s][dt] = (f32x4)(0.0f);
    float m_run[2] = {-3e38f, -3e38f};
    float l_run[2] = {0.0f, 0.0f};

    const float SC = 0.125f * 1.44269504089f;   // 1/sqrt(d) folded with log2(e)

    bf16x8 vreg;

    // ---- prologue: stage tile 0 ----
    g2l16(qkv + (rowbase + rstage) * 3072 + 1024 + h * 64 + kchunk * 8, SM + w * 512);
    vreg = *(const bf16x8*)(qkv + (rowbase + rstage) * 3072 + 2048 + h * 64 + cstage * 8);
    asm volatile("s_waitcnt vmcnt(0)" ::: "memory");
#pragma unroll
    for (int i = 0; i < 8; ++i) {
        const int d = cstage * 8 + i;
        SM[8192 + (((d * 64 + rstage) ^ (((i ^ cstage) & 7) << 3)))] = ((const u16*)&vreg)[i];
    }
    __syncthreads();

    for (int t = 0; t < nt; ++t) {
        const int c = t & 1;
        const int kb = t * 64;
        u16* const Kb = SM + (c ? 4096 : 0);
        u16* const Vb = SM + 8192 + (c ? 4096 : 0);

        // issue next-tile staging (K -> LDS direct, V -> regs) before compute
        if (t + 1 < nt) {
            const int kb2 = kb + 64;
            g2l16(qkv + (rowbase + kb2 + rstage) * 3072 + 1024 + h * 64 + kchunk * 8,
                  SM + (c ? 0 : 4096) + w * 512);
            vreg = *(const bf16x8*)(qkv + (rowbase + kb2 + rstage) * 3072 + 2048 + h * 64 + cstage * 8);
        }

        if (kb <= q0 + w * 32 + 31) {   // wave has at least one visible strip
            // K A-fragments, shared by both strips (swizzled ds_read_b128, key=lr&7)
            bf16x8 kf[4][2];
#pragma unroll
            for (int kt = 0; kt < 4; ++kt)
#pragma unroll
                for (int ks = 0; ks < 2; ++ks)
                    kf[kt][ks] = *(const bf16x8*)&Kb[((kt * 16 + lr) * 64 + ks * 32 + lh * 8) ^ ((lr & 7) << 3)];
#pragma unroll
            for (int s = 0; s < 2; ++s) {
                const int qbase = q0 + w * 32 + s * 16;
                if (kb > qbase + 15) continue;
                // S^T[key][q] = K * Q^T : lane owns q = lr
                f32x4 sf[4];
                __builtin_amdgcn_s_setprio(1);
#pragma unroll
                for (int kt = 0; kt < 4; ++kt) {
                    f32x4 z = (f32x4)(0.0f);
                    z = MFMA16(kf[kt][0], qf[s][0], z, 0, 0, 0);
                    z = MFMA16(kf[kt][1], qf[s][1], z, 0, 0, 0);
                    sf[kt] = z;
                }
                __builtin_amdgcn_s_setprio(0);
                const int qrow = qbase + lr;
                const bool notfull = (kb + 63 > qbase);
                float mt = -3e38f;
#pragma unroll
                for (int kt = 0; kt < 4; ++kt)
#pragma unroll
                    for (int j = 0; j < 4; ++j) {
                        float v = sf[kt][j] * SC;   // exp2 domain
                        if (notfull && (kb + kt * 16 + lh * 4 + j > qrow)) v = -3e38f;
                        sf[kt][j] = v;
                        mt = fmaxf(mt, v);
                    }
                mt = fmaxf(mt, __shfl_xor(mt, 16));
                mt = fmaxf(mt, __shfl_xor(mt, 32));
                const float mn = fmaxf(m_run[s], mt);
                const float alpha = EXP2F(m_run[s] - mn);
                m_run[s] = mn;
                float rs = 0.0f;
#pragma unroll
                for (int kt = 0; kt < 4; ++kt)
#pragma unroll
                    for (int j = 0; j < 4; ++j) {
                        const float pp = EXP2F(sf[kt][j] - mn);
                        sf[kt][j] = pp;
                        rs += pp;
                    }
                rs += __shfl_xor(rs, 16);
                rs += __shfl_xor(rs, 32);
                l_run[s] = l_run[s] * alpha + rs;
#pragma unroll
                for (int dt = 0; dt < 4; ++dt)
#pragma unroll
                    for (int j = 0; j < 4; ++j) ot[s][dt][j] *= alpha;
                // P^T lane-local -> per-wave P_lds [q][key], (q&7) XOR key
#pragma unroll
                for (int kt = 0; kt < 4; ++kt) {
                    u16x4 pk;
#pragma unroll
                    for (int j = 0; j < 4; ++j) pk[j] = f32_to_bf16_bits(sf[kt][j]);
                    *(u16x4*)&PL[(lr * 64 + kt * 16 + lh * 4) ^ ((lr & 7) << 3)] = pk;
                }
                // PV: O^T[d][q] += V^T * P^T
                __builtin_amdgcn_s_setprio(1);
#pragma unroll
                for (int ks = 0; ks < 2; ++ks) {
                    const bf16x8 pb = *(const bf16x8*)&PL[(lr * 64 + ks * 32 + lh * 8) ^ ((lr & 7) << 3)];
#pragma unroll
                    for (int dt = 0; dt < 4; ++dt) {
                        const int vkey = ((lr & 7) ^ (dt * 2 + (lr >> 3))) & 7;
                        const bf16x8 vf = *(const bf16x8*)&Vb[((dt * 16 + lr) * 64 + ks * 32 + lh * 8) ^ (vkey << 3)];
                        ot[s][dt] = MFMA16(vf, pb, ot[s][dt], 0, 0, 0);
                    }
                }
                __builtin_amdgcn_s_setprio(0);
            }
        }

        asm volatile("s_waitcnt vmcnt(0)" ::: "memory");
        __syncthreads();
        if (t + 1 < nt) {
            u16* const Vn = SM + 8192 + (c ? 0 : 4096);
#pragma unroll
            for (int i = 0; i < 8; ++i) {
                const int d = cstage * 8 + i;
                Vn[((d * 64 + rstage) ^ (((i ^ cstage) & 7) << 3))] = ((const u16*)&vreg)[i];
            }
        }
        __syncthreads();
    }

    // ---- epilogue: O^T -> LDS transpose -> coalesced bf16 stores ----
    u16* const out_l = SM + w * 2304;   // [32][72] per wave, reuses K/V/P space
#pragma unroll
    for (int s = 0; s < 2; ++s) {
        const float inv = 1.0f / l_run[s];
#pragma unroll
        for (int dt = 0; dt < 4; ++dt)
#pragma unroll
            for (int j = 0; j < 4; ++j)
                out_l[(s * 16 + lr) * 72 + dt * 16 + lh * 4 + j] =
                    f32_to_bf16_bits(ot[s][dt][j] * inv);
    }
    __syncthreads();
#pragma unroll
    for (int r4 = 0; r4 < 4; ++r4) {
        const int row = r4 * 8 + (l >> 3);
        const bf16x8 v = *(const bf16x8*)&out_l[row * 72 + (l & 7) * 8];
        *(bf16x8*)(ctx + (rowbase + q0 + w * 32 + row) * 1024 + h * 64 + (l & 7) * 8) = v;
    }
}

extern "C" void kernel_launch(void* const* d_in, const int* in_sizes, int n_in,
                              void* d_out, int out_size, void* d_ws, size_t ws_size,
                              hipStream_t stream) {
    const float* x      = (const float*)d_in[0];
    const float* W_qkv  = (const float*)d_in[1];
    const float* b_qkv  = (const float*)d_in[2];
    const float* W_o    = (const float*)d_in[3];
    const float* b_o    = (const float*)d_in[4];
    float* out = (float*)d_out;

    const int M = 4 * 2048;     // 8192 rows
    const int C = 1024;
    u16* qkv   = (u16*)d_ws;                       // [8192][3072]
    u16* xb    = qkv   + (size_t)M * 3 * C;        // [8192][1024]
    u16* wqkvt = xb    + (size_t)M * C;            // [3072][1024]
    u16* ctx   = wqkvt + (size_t)3 * C * C;        // [8192][1024]
    u16* wot   = ctx   + (size_t)M * C;            // [1024][1024]

    cvt_bf16_kernel<<<(M * C) / (256 * 4), 256, 0, stream>>>(x, xb, M * C);
    cvt_t_kernel<<<(3 * C * C) / 256, 256, 0, stream>>>(W_qkv, wqkvt, C, 3 * C);
    cvt_t_kernel<<<(C * C) / 256, 256, 0, stream>>>(W_o, wot, C, C);

    gemm_nt<1><<<dim3(3 * C / 128, M / 128), 256, 0, stream>>>(xb, wqkvt, b_qkv, qkv, M, 3 * C, C);

    attn_kernel<<<512, 512, 0, stream>>>(qkv, ctx);

    gemm_nt<0><<<dim3(C / 128, M / 128), 256, 0, stream>>>(ctx, wot, b_o, out, M, C, C);
}

// Round 6
// 229.058 us; speedup vs baseline: 2.5415x; 1.2653x over previous
//
#include <hip/hip_runtime.h>
#include <hip/hip_bf16.h>

typedef __attribute__((ext_vector_type(8))) __bf16 bf16x8;
typedef __attribute__((ext_vector_type(4))) float f32x4;
typedef __attribute__((ext_vector_type(4))) unsigned short u16x4;
typedef unsigned short u16;

#define MFMA16 __builtin_amdgcn_mfma_f32_16x16x32_bf16

#if __has_builtin(__builtin_amdgcn_exp2f)
#define EXP2F __builtin_amdgcn_exp2f
#else
#define EXP2F(x) __expf((x) * 0.69314718056f)
#endif

__device__ inline u16 f32_to_bf16_bits(float f) {
    unsigned u = __builtin_bit_cast(unsigned, f);
    unsigned r = u + 0x7FFFu + ((u >> 16) & 1u);
    return (u16)(r >> 16);
}

__device__ inline void g2l16(const void* g, void* l) {
    __builtin_amdgcn_global_load_lds(
        (const __attribute__((address_space(1))) unsigned int*)g,
        (__attribute__((address_space(3))) unsigned int*)l,
        16, 0, 0);
}

// ---------------- convert: f32 -> bf16 (vectorized) ----------------
__global__ void cvt_bf16_kernel(const float* __restrict__ in, u16* __restrict__ out, int n) {
    int i = (blockIdx.x * 256 + threadIdx.x) * 4;
    if (i >= n) return;
    f32x4 v = *(const f32x4*)&in[i];
    u16x4 r;
#pragma unroll
    for (int j = 0; j < 4; ++j) r[j] = f32_to_bf16_bits(v[j]);
    *(u16x4*)&out[i] = r;
}

// ---------------- convert + transpose: W[K][N] f32 -> WT[N][K] bf16 ----------------
__global__ void cvt_t_kernel(const float* __restrict__ W, u16* __restrict__ WT, int K, int N) {
    int idx = blockIdx.x * 256 + threadIdx.x;
    int k = idx / N;
    int n = idx - k * N;
    WT[(size_t)n * K + k] = f32_to_bf16_bits(W[idx]);
}

// ---------------- GEMM: C[M][N] = A[M][K] * BT[N][K]^T + bias ----------------
template <int STORE_BF16>
__global__ __launch_bounds__(256) void gemm_nt(
    const u16* __restrict__ A, const u16* __restrict__ BT,
    const float* __restrict__ bias, void* __restrict__ Cv,
    int M, int N, int K)
{
    __shared__ __align__(16) u16 As[128 * 64];
    __shared__ __align__(16) u16 Bs[128 * 64];
    const int tid = threadIdx.x;
    const int w = tid >> 6, l = tid & 63;
    const int lr = l & 15, lh = l >> 4;
    const int wr = (w >> 1) * 64, wc = (w & 1) * 64;
    const int m0 = blockIdx.y * 128, n0 = blockIdx.x * 128;

    f32x4 acc[4][4];
#pragma unroll
    for (int m = 0; m < 4; ++m)
#pragma unroll
        for (int n = 0; n < 4; ++n) acc[m][n] = (f32x4)(0.0f);

    for (int k0 = 0; k0 < K; k0 += 64) {
        __syncthreads();
#pragma unroll
        for (int p = 0; p < 4; ++p) {
            int f = p * 256 + tid;
            int r = f >> 3, kk = (f & 7) << 3;
            g2l16(A + (size_t)(m0 + r) * K + (k0 + kk), &As[(p * 4 + w) * 512]);
            g2l16(BT + (size_t)(n0 + r) * K + (k0 + kk), &Bs[(p * 4 + w) * 512]);
        }
        __syncthreads();
#pragma unroll
        for (int ks = 0; ks < 2; ++ks) {
            bf16x8 af[4], bfr[4];
#pragma unroll
            for (int m = 0; m < 4; ++m)
                af[m] = *(const bf16x8*)&As[(wr + m * 16 + lr) * 64 + ks * 32 + lh * 8];
#pragma unroll
            for (int n = 0; n < 4; ++n)
                bfr[n] = *(const bf16x8*)&Bs[(wc + n * 16 + lr) * 64 + ks * 32 + lh * 8];
#pragma unroll
            for (int m = 0; m < 4; ++m)
#pragma unroll
                for (int n = 0; n < 4; ++n)
                    acc[m][n] = MFMA16(af[m], bfr[n], acc[m][n], 0, 0, 0);
        }
    }

#pragma unroll
    for (int m = 0; m < 4; ++m) {
        int row = m0 + wr + m * 16 + lh * 4;
#pragma unroll
        for (int n = 0; n < 4; ++n) {
            int col = n0 + wc + n * 16 + lr;
            float bs = bias[col];
#pragma unroll
            for (int j = 0; j < 4; ++j) {
                float v = acc[m][n][j] + bs;
                if (STORE_BF16)
                    ((u16*)Cv)[(size_t)(row + j) * N + col] = f32_to_bf16_bits(v);
                else
                    ((float*)Cv)[(size_t)(row + j) * N + col] = v;
            }
        }
    }
}

// ---------------- causal flash attention v4 ----------------
// QBLK=256 (8 waves x 32 rows), KVBLK=64. Swapped QK^T (S^T = K*Q^T).
// Triangle pairing: each block processes q-tiles qt and 7-qt -> uniform 36
// tile-steps/block, grid 256 (1/CU). K dbuf LDS via global_load_lds with
// per-row XOR swizzle; V reg-staged into swizzled VT. exp2-domain online
// softmax with defer-max (T13, THR=16).
__global__ __launch_bounds__(512, 2) void attn_kernel(
    const u16* __restrict__ qkv, u16* __restrict__ ctx)
{
    __shared__ __align__(16) u16 SM[24576];   // K dbuf 8K | V dbuf 8K | P 8x1K (u16)

    const int bid = blockIdx.x;
    const int swz = (bid & 7) * 32 + (bid >> 3);   // 8 heads per XCD
    const int bh = swz >> 2;
    const int pr = swz & 3;                        // pair index: qt = pr, then 7-pr
    const int b = bh >> 4, h = bh & 15;
    const size_t rowbase = (size_t)b * 2048;
    const int tid = threadIdx.x, w = tid >> 6, l = tid & 63;
    const int lr = l & 15, lh = l >> 4;
    u16* const PL = SM + 16384 + w * 1024;         // [16][64] per wave, (q&7) key

    // staging geometry: wave w stages rows w*8..w*8+7 of the 64-row K/V tile
    const int rstage = w * 8 + (l >> 3);
    const int cstage = l & 7;                       // dest col-chunk
    const int kchunk = cstage ^ (l >> 3);           // inverse-swizzle src chunk (key=row&7)

    const float SC = 0.125f * 1.44269504089f;   // 1/sqrt(d) folded with log2(e)
    bf16x8 vreg;

#pragma unroll
    for (int pass = 0; pass < 2; ++pass) {
        const int qt = pass ? (7 - pr) : pr;
        const int q0 = qt * 256;
        const int nt = 4 * qt + 4;

        // Q fragments (MFMA B-operand): lane holds Q[q=base+lr][k=lh*8..+7 (+ks*32)]
        bf16x8 qf[2][2];
#pragma unroll
        for (int s = 0; s < 2; ++s) {
            const u16* qp = qkv + (rowbase + q0 + w * 32 + s * 16 + lr) * 3072 + h * 64 + lh * 8;
            qf[s][0] = *(const bf16x8*)qp;
            qf[s][1] = *(const bf16x8*)(qp + 32);
        }

        f32x4 ot[2][4];
#pragma unroll
        for (int s = 0; s < 2; ++s)
#pragma unroll
            for (int dt = 0; dt < 4; ++dt) ot[s][dt] = (f32x4)(0.0f);
        float m_run[2] = {-3e38f, -3e38f};
        float l_run[2] = {0.0f, 0.0f};

        // ---- prologue: stage tile 0 (barrier: protect SM vs prior pass epilogue) ----
        __syncthreads();
        g2l16(qkv + (rowbase + rstage) * 3072 + 1024 + h * 64 + kchunk * 8, SM + w * 512);
        vreg = *(const bf16x8*)(qkv + (rowbase + rstage) * 3072 + 2048 + h * 64 + cstage * 8);
        asm volatile("s_waitcnt vmcnt(0)" ::: "memory");
#pragma unroll
        for (int i = 0; i < 8; ++i) {
            const int d = cstage * 8 + i;
            SM[8192 + (((d * 64 + rstage) ^ (((i ^ cstage) & 7) << 3)))] = ((const u16*)&vreg)[i];
        }
        __syncthreads();

        for (int t = 0; t < nt; ++t) {
            const int c = t & 1;
            const int kb = t * 64;
            u16* const Kb = SM + (c ? 4096 : 0);
            u16* const Vb = SM + 8192 + (c ? 4096 : 0);

            // issue next-tile staging (K -> LDS direct, V -> regs) before compute
            if (t + 1 < nt) {
                const int kb2 = kb + 64;
                g2l16(qkv + (rowbase + kb2 + rstage) * 3072 + 1024 + h * 64 + kchunk * 8,
                      SM + (c ? 0 : 4096) + w * 512);
                vreg = *(const bf16x8*)(qkv + (rowbase + kb2 + rstage) * 3072 + 2048 + h * 64 + cstage * 8);
            }

            if (kb <= q0 + w * 32 + 31) {   // wave has at least one visible strip
                // K A-fragments, shared by both strips (swizzled ds_read_b128, key=lr&7)
                bf16x8 kf[4][2];
#pragma unroll
                for (int kt = 0; kt < 4; ++kt)
#pragma unroll
                    for (int ks = 0; ks < 2; ++ks)
                        kf[kt][ks] = *(const bf16x8*)&Kb[((kt * 16 + lr) * 64 + ks * 32 + lh * 8) ^ ((lr & 7) << 3)];
#pragma unroll
                for (int s = 0; s < 2; ++s) {
                    const int qbase = q0 + w * 32 + s * 16;
                    if (kb > qbase + 15) continue;
                    // S^T[key][q] = K * Q^T : lane owns q = lr
                    f32x4 sf[4];
                    __builtin_amdgcn_s_setprio(1);
#pragma unroll
                    for (int kt = 0; kt < 4; ++kt) {
                        f32x4 z = (f32x4)(0.0f);
                        z = MFMA16(kf[kt][0], qf[s][0], z, 0, 0, 0);
                        z = MFMA16(kf[kt][1], qf[s][1], z, 0, 0, 0);
                        sf[kt] = z;
                    }
                    __builtin_amdgcn_s_setprio(0);
                    const int qrow = qbase + lr;
                    const bool notfull = (kb + 63 > qbase);
                    float mt = -3e38f;
#pragma unroll
                    for (int kt = 0; kt < 4; ++kt)
#pragma unroll
                        for (int j = 0; j < 4; ++j) {
                            float v = sf[kt][j] * SC;   // exp2 domain
                            if (notfull && (kb + kt * 16 + lh * 4 + j > qrow)) v = -3e38f;
                            sf[kt][j] = v;
                            mt = fmaxf(mt, v);
                        }
                    mt = fmaxf(mt, __shfl_xor(mt, 16));
                    mt = fmaxf(mt, __shfl_xor(mt, 32));

                    // defer-max (T13): skip rescale when max didn't grow by >16
                    const bool defer = __all(mt <= m_run[s] + 16.0f);
                    float mn = m_run[s];
                    if (!defer) {
                        mn = fmaxf(m_run[s], mt);
                        const float alpha = EXP2F(m_run[s] - mn);
                        m_run[s] = mn;
                        l_run[s] *= alpha;
#pragma unroll
                        for (int dt = 0; dt < 4; ++dt)
#pragma unroll
                            for (int j = 0; j < 4; ++j) ot[s][dt][j] *= alpha;
                    }
                    float rs = 0.0f;
#pragma unroll
                    for (int kt = 0; kt < 4; ++kt)
#pragma unroll
                        for (int j = 0; j < 4; ++j) {
                            const float pp = EXP2F(sf[kt][j] - mn);
                            sf[kt][j] = pp;
                            rs += pp;
                        }
                    rs += __shfl_xor(rs, 16);
                    rs += __shfl_xor(rs, 32);
                    l_run[s] += rs;
                    // P^T lane-local -> per-wave P_lds [q][key], (q&7) XOR key
#pragma unroll
                    for (int kt = 0; kt < 4; ++kt) {
                        u16x4 pk;
#pragma unroll
                        for (int j = 0; j < 4; ++j) pk[j] = f32_to_bf16_bits(sf[kt][j]);
                        *(u16x4*)&PL[(lr * 64 + kt * 16 + lh * 4) ^ ((lr & 7) << 3)] = pk;
                    }
                    // PV: O^T[d][q] += V^T * P^T
                    __builtin_amdgcn_s_setprio(1);
#pragma unroll
                    for (int ks = 0; ks < 2; ++ks) {
                        const bf16x8 pb = *(const bf16x8*)&PL[(lr * 64 + ks * 32 + lh * 8) ^ ((lr & 7) << 3)];
#pragma unroll
                        for (int dt = 0; dt < 4; ++dt) {
                            const int vkey = ((lr & 7) ^ (dt * 2 + (lr >> 3))) & 7;
                            const bf16x8 vf = *(const bf16x8*)&Vb[((dt * 16 + lr) * 64 + ks * 32 + lh * 8) ^ (vkey << 3)];
                            ot[s][dt] = MFMA16(vf, pb, ot[s][dt], 0, 0, 0);
                        }
                    }
                    __builtin_amdgcn_s_setprio(0);
                }
            }

            asm volatile("s_waitcnt vmcnt(0)" ::: "memory");
            __syncthreads();
            if (t + 1 < nt) {
                u16* const Vn = SM + 8192 + (c ? 0 : 4096);
#pragma unroll
                for (int i = 0; i < 8; ++i) {
                    const int d = cstage * 8 + i;
                    Vn[((d * 64 + rstage) ^ (((i ^ cstage) & 7) << 3))] = ((const u16*)&vreg)[i];
                }
            }
            __syncthreads();
        }

        // ---- epilogue: O^T -> LDS transpose -> coalesced bf16 stores ----
        u16* const out_l = SM + w * 2304;   // [32][72] per wave, reuses K/V/P space
#pragma unroll
        for (int s = 0; s < 2; ++s) {
            const float inv = 1.0f / l_run[s];
#pragma unroll
            for (int dt = 0; dt < 4; ++dt)
#pragma unroll
                for (int j = 0; j < 4; ++j)
                    out_l[(s * 16 + lr) * 72 + dt * 16 + lh * 4 + j] =
                        f32_to_bf16_bits(ot[s][dt][j] * inv);
        }
        __syncthreads();
#pragma unroll
        for (int r4 = 0; r4 < 4; ++r4) {
            const int row = r4 * 8 + (l >> 3);
            const bf16x8 v = *(const bf16x8*)&out_l[row * 72 + (l & 7) * 8];
            *(bf16x8*)(ctx + (rowbase + q0 + w * 32 + row) * 1024 + h * 64 + (l & 7) * 8) = v;
        }
    }
}

extern "C" void kernel_launch(void* const* d_in, const int* in_sizes, int n_in,
                              void* d_out, int out_size, void* d_ws, size_t ws_size,
                              hipStream_t stream) {
    const float* x      = (const float*)d_in[0];
    const float* W_qkv  = (const float*)d_in[1];
    const float* b_qkv  = (const float*)d_in[2];
    const float* W_o    = (const float*)d_in[3];
    const float* b_o    = (const float*)d_in[4];
    float* out = (float*)d_out;

    const int M = 4 * 2048;     // 8192 rows
    const int C = 1024;
    u16* qkv   = (u16*)d_ws;                       // [8192][3072]
    u16* xb    = qkv   + (size_t)M * 3 * C;        // [8192][1024]
    u16* wqkvt = xb    + (size_t)M * C;            // [3072][1024]
    u16* ctx   = wqkvt + (size_t)3 * C * C;        // [8192][1024]
    u16* wot   = ctx   + (size_t)M * C;            // [1024][1024]

    cvt_bf16_kernel<<<(M * C) / (256 * 4), 256, 0, stream>>>(x, xb, M * C);
    cvt_t_kernel<<<(3 * C * C) / 256, 256, 0, stream>>>(W_qkv, wqkvt, C, 3 * C);
    cvt_t_kernel<<<(C * C) / 256, 256, 0, stream>>>(W_o, wot, C, C);

    gemm_nt<1><<<dim3(3 * C / 128, M / 128), 256, 0, stream>>>(xb, wqkvt, b_qkv, qkv, M, 3 * C, C);

    attn_kernel<<<256, 512, 0, stream>>>(qkv, ctx);

    gemm_nt<0><<<dim3(C / 128, M / 128), 256, 0, stream>>>(ctx, wot, b_o, out, M, C, C);
}